// Round 1
// baseline (2518.872 us; speedup 1.0000x reference)
//
#include <hip/hip_runtime.h>
#include <math.h>

#define TSEQ_MAX 256

__device__ __forceinline__ float sigmf(float x){ return 1.f/(1.f+__expf(-x)); }
__device__ __forceinline__ float tanh_f(float x){ return 1.f - 2.f/(__expf(2.f*x)+1.f); }

// ---------------- GCN degree / norm ----------------
__global__ void k_deg_init(float* deg, int N){
    int i = blockIdx.x*256 + threadIdx.x;
    if (i < N) deg[i] = 1.0f;              // self-loop weight
}
__global__ void k_deg_acc(const int* __restrict__ ei, const float* __restrict__ ew, float* deg, int E){
    int e = blockIdx.x*256 + threadIdx.x;
    if (e < E) atomicAdd(&deg[ei[E + e]], ew[e]);
}
__global__ void k_dis(float* deg, int N){
    int i = blockIdx.x*256 + threadIdx.x;
    if (i < N){ float d = deg[i]; deg[i] = (d > 0.f) ? rsqrtf(fmaxf(d, 1e-12f)) : 0.f; }
}

// ---------------- GCN layer 1: xw1 = feats@W1 ; out1 = b1 + dis^2*xw1 ----------------
__global__ __launch_bounds__(256) void k_xw1(const float* __restrict__ xc, const float* __restrict__ te,
        const float* __restrict__ emb, const float* __restrict__ W1, const float* __restrict__ b1,
        const float* __restrict__ dis, float* __restrict__ xw1, float* __restrict__ out1, int N){
    __shared__ float Ws[134*64];
    __shared__ float fs[4][136];
    int tid = threadIdx.x;
    for (int i = tid; i < 134*64; i += 256) Ws[i] = W1[i];
    int sub = tid >> 6, lane = tid & 63;
    int node = blockIdx.x*4 + sub;
    if (node < N){
        fs[sub][2+lane]      = emb[node*128 + lane];
        fs[sub][2+64+lane]   = emb[node*128 + 64 + lane];
        if (lane < 2) fs[sub][lane]       = xc[node*2 + lane];
        if (lane < 4) fs[sub][130 + lane] = te[node*4 + lane];
    }
    __syncthreads();
    if (node < N){
        float acc = 0.f;
        #pragma unroll 2
        for (int k = 0; k < 134; k++) acc += fs[sub][k] * Ws[k*64 + lane];
        float d = dis[node];
        xw1[node*64 + lane]  = acc;
        out1[node*64 + lane] = b1[lane] + d*d*acc;
    }
}

// ---------------- GCN edge aggregation, 64 channels ----------------
__global__ void k_agg1(const int* __restrict__ ei, const float* __restrict__ ew,
        const float* __restrict__ dis, const float* __restrict__ xw1, float* out1, int E){
    int idx = blockIdx.x*4 + (threadIdx.x >> 6);
    int lane = threadIdx.x & 63;
    if (idx >= E) return;
    int r = ei[idx], c = ei[E + idx];
    float nrm = dis[r] * ew[idx] * dis[c];
    atomicAdd(&out1[c*64 + lane], nrm * xw1[r*64 + lane]);
}

// ---------------- GCN layer 2: z1=relu(out1); xw2=z1@W2; zinit=b2+dis^2*xw2 ----------------
__global__ __launch_bounds__(256) void k_xw2(const float* __restrict__ out1, const float* __restrict__ W2,
        const float* __restrict__ b2, const float* __restrict__ dis,
        float* __restrict__ xw2, float* __restrict__ zinit, int N){
    __shared__ float Ws[64*128];
    __shared__ float zs[2][68];
    int tid = threadIdx.x;
    for (int i = tid; i < 64*128; i += 256) Ws[i] = W2[i];
    int sub = tid >> 7, lane = tid & 127;
    int node = blockIdx.x*2 + sub;
    if (node < N && lane < 64) zs[sub][lane] = fmaxf(out1[node*64 + lane], 0.f);
    __syncthreads();
    if (node < N){
        float acc = 0.f;
        #pragma unroll 4
        for (int k = 0; k < 64; k++) acc += zs[sub][k] * Ws[k*128 + lane];
        float d = dis[node];
        xw2[node*128 + lane]   = acc;
        zinit[node*128 + lane] = b2[lane] + d*d*acc;
    }
}

// ---------------- GCN edge aggregation, 128 channels ----------------
__global__ void k_agg2(const int* __restrict__ ei, const float* __restrict__ ew,
        const float* __restrict__ dis, const float* __restrict__ xw2, float* z, int E){
    int idx = blockIdx.x*2 + (threadIdx.x >> 7);
    int lane = threadIdx.x & 127;
    if (idx >= E) return;
    int r = ei[idx], c = ei[E + idx];
    float nrm = dis[r] * ew[idx] * dis[c];
    atomicAdd(&z[c*128 + lane], nrm * xw2[r*128 + lane]);
}

// ---------------- build x = [z[seq] | dur_emb] ----------------
__global__ void k_build_x(const float* __restrict__ z, const int* __restrict__ seq,
        const float* __restrict__ dur, const float* __restrict__ dW1, const float* __restrict__ db1,
        const float* __restrict__ dW2, const float* __restrict__ db2, float* __restrict__ x){
    int row = blockIdx.x;
    int tid = threadIdx.x;       // 192 threads
    if (tid < 128){
        int node = seq[row];
        x[row*160 + tid] = z[node*128 + tid];
    } else if (tid < 160){
        int jj = tid - 128;
        float ld = log1pf(dur[row]);
        float acc = db2[jj];
        #pragma unroll
        for (int hh = 0; hh < 16; hh++){
            float hv = fmaxf(ld * dW1[hh] + db1[hh], 0.f);
            acc += hv * dW2[hh*32 + jj];
        }
        x[row*160 + tid] = acc;
    }
}

// ---------------- transpose Wih (512x160 -> 160x512), both dirs ----------------
__global__ void k_transpose_wih(const float* __restrict__ Wf, const float* __restrict__ Wb,
        float* __restrict__ Tf, float* __restrict__ Tb){
    int idx = blockIdx.x*256 + threadIdx.x;
    if (idx < 512*160){
        int g = idx / 160, k = idx % 160;
        Tf[k*512 + g] = Wf[idx];
        Tb[k*512 + g] = Wb[idx];
    }
}

// ---------------- generic f32 GEMM: C[M,N] = A[M,K] @ B[K,N] + bias[N] ----------------
// M % 64 == 0, K % 16 == 0, N % 4 == 0 (bounds-checked on N).
#define MT 64
#define NT 128
#define KC 16
__global__ __launch_bounds__(256) void k_gemm(const float* __restrict__ A, const float* __restrict__ B,
        const float* __restrict__ bias, float* __restrict__ C, int M, int Nn, int K){
    __shared__ float As[KC][MT+4];
    __shared__ float Bs[KC][NT+4];
    int tid = threadIdx.x;
    int n0 = blockIdx.x * NT;
    int m0 = blockIdx.y * MT;
    int tn = tid & 31;
    int tm = tid >> 5;
    float acc[8][4];
    #pragma unroll
    for (int i = 0; i < 8; i++)
        #pragma unroll
        for (int j = 0; j < 4; j++) acc[i][j] = 0.f;

    for (int kt = 0; kt < K; kt += KC){
        {   // stage A (64 x 16), transposed into As[k][m]
            int m = tid >> 2, q = tid & 3;
            float4 a4 = *(const float4*)(A + (size_t)(m0+m)*K + kt + q*4);
            As[q*4+0][m] = a4.x; As[q*4+1][m] = a4.y; As[q*4+2][m] = a4.z; As[q*4+3][m] = a4.w;
        }
        {   // stage B (16 x 128)
            #pragma unroll
            for (int i = 0; i < 2; i++){
                int idx = tid*2 + i;
                int r = idx >> 5, c4 = idx & 31;
                int col = n0 + c4*4;
                float4 bv = make_float4(0.f,0.f,0.f,0.f);
                if (col < Nn) bv = *(const float4*)(B + (size_t)(kt+r)*Nn + col);
                *(float4*)(&Bs[r][c4*4]) = bv;
            }
        }
        __syncthreads();
        #pragma unroll
        for (int k = 0; k < KC; k++){
            float4 b4 = *(const float4*)(&Bs[k][tn*4]);
            float4 a0 = *(const float4*)(&As[k][tm*8]);
            float4 a1 = *(const float4*)(&As[k][tm*8+4]);
            float av[8] = {a0.x,a0.y,a0.z,a0.w,a1.x,a1.y,a1.z,a1.w};
            float bv[4] = {b4.x,b4.y,b4.z,b4.w};
            #pragma unroll
            for (int i = 0; i < 8; i++)
                #pragma unroll
                for (int j = 0; j < 4; j++) acc[i][j] += av[i]*bv[j];
        }
        __syncthreads();
    }
    int col = n0 + tn*4;
    if (col < Nn){
        float4 bb = *(const float4*)(bias + col);
        #pragma unroll
        for (int i = 0; i < 8; i++){
            int row = m0 + tm*8 + i;
            float4 o = make_float4(acc[i][0]+bb.x, acc[i][1]+bb.y, acc[i][2]+bb.z, acc[i][3]+bb.w);
            *(float4*)(C + (size_t)row*Nn + col) = o;
        }
    }
}

// ---------------- LSTM recurrence: one block per (batch row, direction) ----------------
__global__ __launch_bounds__(512) void k_lstm(const float* __restrict__ xg_f, const float* __restrict__ xg_b,
        const float* __restrict__ Whh_f, const float* __restrict__ Whh_b,
        const int* __restrict__ lengths, float* __restrict__ lstm_out, int T){
    int b = blockIdx.x;
    int dir = blockIdx.y;
    const float* xg  = dir ? xg_b  : xg_f;
    const float* Whh = dir ? Whh_b : Whh_f;
    int len = lengths[b];
    int j = threadIdx.x;
    __shared__ __align__(16) float h[128];
    __shared__ float g[512];
    float4 w[32];
    const float4* wrow = (const float4*)(Whh + j*128);
    #pragma unroll
    for (int k = 0; k < 32; k++) w[k] = wrow[k];
    if (j < 128) h[j] = 0.f;
    float c = 0.f;
    __syncthreads();
    for (int s = 0; s < len; s++){
        int t = dir ? (len-1-s) : s;
        float acc = xg[((size_t)b*T + t)*512 + j];
        const float4* h4 = (const float4*)h;
        #pragma unroll
        for (int k = 0; k < 32; k++){
            float4 hv = h4[k];
            acc += w[k].x*hv.x + w[k].y*hv.y + w[k].z*hv.z + w[k].w*hv.w;
        }
        g[j] = acc;
        __syncthreads();
        if (j < 128){
            float gi = g[j], gf = g[128+j], gg = g[256+j], go = g[384+j];
            float cn = sigmf(gf)*c + sigmf(gi)*tanh_f(gg);
            float hn = sigmf(go)*tanh_f(cn);
            c = cn;
            h[j] = hn;
            lstm_out[((size_t)b*T + t)*256 + dir*128 + j] = hn;
        }
        __syncthreads();
    }
}

// ---------------- attention + context ----------------
__global__ __launch_bounds__(256) void k_attn(const float* __restrict__ lstm_out,
        const float* __restrict__ attn_W, const int* __restrict__ lengths,
        float* __restrict__ context, int T){
    int b = blockIdx.x;
    int tid = threadIdx.x;
    int len = lengths[b];
    __shared__ float sc[TSEQ_MAX];
    __shared__ float red[8];
    int lane = tid & 63, wv = tid >> 6;
    float a0 = attn_W[lane], a1 = attn_W[64+lane], a2 = attn_W[128+lane], a3 = attn_W[192+lane];
    for (int t = wv; t < len; t += 4){
        const float* r = lstm_out + ((size_t)b*T + t)*256;
        float p = r[lane]*a0 + r[64+lane]*a1 + r[128+lane]*a2 + r[192+lane]*a3;
        #pragma unroll
        for (int o = 32; o > 0; o >>= 1) p += __shfl_down(p, o);
        if (lane == 0) sc[t] = p;
    }
    __syncthreads();
    float v = (tid < len) ? sc[tid] : -INFINITY;
    float m = v;
    #pragma unroll
    for (int o = 32; o > 0; o >>= 1) m = fmaxf(m, __shfl_down(m, o));
    if (lane == 0) red[wv] = m;
    __syncthreads();
    float M4 = fmaxf(fmaxf(red[0],red[1]), fmaxf(red[2],red[3]));
    float e = (tid < len) ? __expf(v - M4) : 0.f;
    float ss = e;
    #pragma unroll
    for (int o = 32; o > 0; o >>= 1) ss += __shfl_down(ss, o);
    if (lane == 0) red[4+wv] = ss;
    __syncthreads();
    float S = red[4]+red[5]+red[6]+red[7];
    sc[tid] = e / S;
    __syncthreads();
    float acc = 0.f;
    for (int t = 0; t < len; t++) acc += sc[t] * lstm_out[((size_t)b*T + t)*256 + tid];
    context[b*256 + tid] = acc;
}

extern "C" void kernel_launch(void* const* d_in, const int* in_sizes, int n_in,
                              void* d_out, int out_size, void* d_ws, size_t ws_size,
                              hipStream_t stream) {
    const float* x_coords  = (const float*)d_in[0];
    const float* temporal  = (const float*)d_in[1];
    const int*   edge_idx  = (const int*)  d_in[2];
    const float* edge_w    = (const float*)d_in[3];
    const int*   seq       = (const int*)  d_in[4];
    const float* durations = (const float*)d_in[5];
    const int*   lengths   = (const int*)  d_in[6];
    const float* node_emb  = (const float*)d_in[7];
    const float* gcn1_W    = (const float*)d_in[8];
    const float* gcn1_b    = (const float*)d_in[9];
    const float* gcn2_W    = (const float*)d_in[10];
    const float* gcn2_b    = (const float*)d_in[11];
    const float* dur_W1    = (const float*)d_in[12];
    const float* dur_b1    = (const float*)d_in[13];
    const float* dur_W2    = (const float*)d_in[14];
    const float* dur_b2    = (const float*)d_in[15];
    const float* Wih_f     = (const float*)d_in[16];
    const float* Whh_f     = (const float*)d_in[17];
    const float* b_f       = (const float*)d_in[18];
    const float* Wih_b     = (const float*)d_in[19];
    const float* Whh_b     = (const float*)d_in[20];
    const float* b_b       = (const float*)d_in[21];
    const float* attn_W    = (const float*)d_in[22];
    const float* fc_W      = (const float*)d_in[24];
    const float* fc_b      = (const float*)d_in[25];
    float* out = (float*)d_out;
    float* ws  = (float*)d_ws;

    const int N  = in_sizes[0] / 2;      // 100000
    const int E  = in_sizes[2] / 2;      // 1600000
    const int B  = in_sizes[6];          // 256
    const int T  = in_sizes[4] / B;      // 200
    const int BT = B * T;                // 51200

    // workspace layout (floats). GCN temporaries overlaid under xg buffers (dead by then).
    float* xg_f     = ws + 0;                       // 26,214,400
    float* xg_b     = ws + 26214400;                // 26,214,400
    float* xbuf     = ws + 52428800;                //  8,192,000
    float* lstm_out = ws + 60620800;                // 13,107,200
    float* context  = ws + 73728000;                //     65,536
    float* WihT_f   = ws + 73793536;                //     81,920
    float* WihT_b   = ws + 73875456;                //     81,920  (total 73,957,376 floats = 296 MB)
    float* dis  = ws + 0;            // overlaid, dead before xg written
    float* xw1  = ws + 100352;
    float* out1 = ws + 6500352;
    float* xw2  = ws + 12900352;
    float* zbuf = ws + 25700352;

    // ---- GCN normalization ----
    k_deg_init<<<dim3((N+255)/256), dim3(256), 0, stream>>>(dis, N);
    k_deg_acc <<<dim3((E+255)/256), dim3(256), 0, stream>>>(edge_idx, edge_w, dis, E);
    k_dis     <<<dim3((N+255)/256), dim3(256), 0, stream>>>(dis, N);

    // ---- GCN layer 1 ----
    k_xw1 <<<dim3((N+3)/4), dim3(256), 0, stream>>>(x_coords, temporal, node_emb, gcn1_W, gcn1_b, dis, xw1, out1, N);
    k_agg1<<<dim3((E+3)/4), dim3(256), 0, stream>>>(edge_idx, edge_w, dis, xw1, out1, E);

    // ---- GCN layer 2 ----
    k_xw2 <<<dim3((N+1)/2), dim3(256), 0, stream>>>(out1, gcn2_W, gcn2_b, dis, xw2, zbuf, N);
    k_agg2<<<dim3((E+1)/2), dim3(256), 0, stream>>>(edge_idx, edge_w, dis, xw2, zbuf, E);

    // ---- sequence features ----
    k_build_x<<<dim3(BT), dim3(192), 0, stream>>>(zbuf, seq, durations, dur_W1, dur_b1, dur_W2, dur_b2, xbuf);

    // ---- input-gate GEMMs ----
    k_transpose_wih<<<dim3(320), dim3(256), 0, stream>>>(Wih_f, Wih_b, WihT_f, WihT_b);
    k_gemm<<<dim3(512/NT, BT/MT), dim3(256), 0, stream>>>(xbuf, WihT_f, b_f, xg_f, BT, 512, 160);
    k_gemm<<<dim3(512/NT, BT/MT), dim3(256), 0, stream>>>(xbuf, WihT_b, b_b, xg_b, BT, 512, 160);

    // ---- BiLSTM recurrence ----
    k_lstm<<<dim3(B, 2), dim3(512), 0, stream>>>(xg_f, xg_b, Whh_f, Whh_b, lengths, lstm_out, T);

    // ---- attention ----
    k_attn<<<dim3(B), dim3(256), 0, stream>>>(lstm_out, attn_W, lengths, context, T);

    // ---- final FC: (256 x 256) @ (256 x 100000) + fc_b ----
    k_gemm<<<dim3((N + NT - 1)/NT, B/MT), dim3(256), 0, stream>>>(context, fc_W, fc_b, out, B, N, 256);
}

// Round 2
// 1994.422 us; speedup vs baseline: 1.2630x; 1.2630x over previous
//
#include <hip/hip_runtime.h>
#include <math.h>

#define TSEQ_MAX 256

__device__ __forceinline__ float sigmf(float x){ return 1.f/(1.f+__expf(-x)); }
__device__ __forceinline__ float tanh_f(float x){ return 1.f - 2.f/(__expf(2.f*x)+1.f); }

// ---------------- GCN degree / norm ----------------
__global__ void k_deg_init(float* deg, int N){
    int i = blockIdx.x*256 + threadIdx.x;
    if (i < N) deg[i] = 1.0f;              // self-loop weight
}
__global__ void k_deg_acc(const int* __restrict__ ei, const float* __restrict__ ew, float* deg, int E){
    int e = blockIdx.x*256 + threadIdx.x;
    if (e < E) atomicAdd(&deg[ei[E + e]], ew[e]);
}
__global__ void k_dis(float* deg, int N){
    int i = blockIdx.x*256 + threadIdx.x;
    if (i < N){ float d = deg[i]; deg[i] = (d > 0.f) ? rsqrtf(fmaxf(d, 1e-12f)) : 0.f; }
}

// ---------------- CSR build: count, scan, scatter ----------------
__global__ void k_count(const int* __restrict__ ei, int* __restrict__ cnt, int E){
    int e = blockIdx.x*256 + threadIdx.x;
    if (e < E) atomicAdd(&cnt[ei[E + e]], 1);
}

// scan1: 1024 elements per block (256 thr x 4), exclusive within block + block totals
__global__ __launch_bounds__(256) void k_scan1(const int* __restrict__ cnt, int* __restrict__ base,
        int* __restrict__ partials, int N){
    __shared__ int sh[256];
    int tid = threadIdx.x;
    int i0 = blockIdx.x*1024 + tid*4;
    int v0=0,v1=0,v2=0,v3=0;
    if (i0+0 < N) v0 = cnt[i0+0];
    if (i0+1 < N) v1 = cnt[i0+1];
    if (i0+2 < N) v2 = cnt[i0+2];
    if (i0+3 < N) v3 = cnt[i0+3];
    int tsum = v0+v1+v2+v3;
    sh[tid] = tsum;
    __syncthreads();
    for (int off = 1; off < 256; off <<= 1){
        int val = (tid >= off) ? sh[tid-off] : 0;
        __syncthreads();
        sh[tid] += val;
        __syncthreads();
    }
    int excl = sh[tid] - tsum;
    if (i0+0 < N) base[i0+0] = excl;
    if (i0+1 < N) base[i0+1] = excl + v0;
    if (i0+2 < N) base[i0+2] = excl + v0 + v1;
    if (i0+3 < N) base[i0+3] = excl + v0 + v1 + v2;
    if (tid == 255) partials[blockIdx.x] = sh[255];
}
__global__ __launch_bounds__(128) void k_scan2(int* partials, int nb){
    __shared__ int sh[128];
    int tid = threadIdx.x;
    int v = (tid < nb) ? partials[tid] : 0;
    sh[tid] = v;
    __syncthreads();
    for (int off = 1; off < 128; off <<= 1){
        int val = (tid >= off) ? sh[tid-off] : 0;
        __syncthreads();
        sh[tid] += val;
        __syncthreads();
    }
    if (tid < nb) partials[tid] = sh[tid] - v;   // exclusive
}
__global__ void k_scan3(int* base, int* cursor, const int* __restrict__ partials, int N, int E){
    int i = blockIdx.x*256 + threadIdx.x;
    if (i < N){
        int v = base[i] + partials[i >> 10];
        base[i] = v; cursor[i] = v;
    }
    if (i == N) base[N] = E;
}
__global__ void k_scatter(const int* __restrict__ ei, const float* __restrict__ ew,
        const float* __restrict__ dis, int* cursor, int2* __restrict__ sorted, int E){
    int e = blockIdx.x*256 + threadIdx.x;
    if (e < E){
        int r = ei[e], c = ei[E + e];
        float nrm = dis[r] * ew[e] * dis[c];
        int pos = atomicAdd(&cursor[c], 1);
        sorted[pos] = make_int2(r, __float_as_int(nrm));
    }
}

// ---------------- GCN layer 1: xw1 = feats@W1 ----------------
__global__ __launch_bounds__(256) void k_xw1(const float* __restrict__ xc, const float* __restrict__ te,
        const float* __restrict__ emb, const float* __restrict__ W1,
        float* __restrict__ xw1, int N){
    __shared__ float Ws[134*64];
    __shared__ float fs[4][136];
    int tid = threadIdx.x;
    for (int i = tid; i < 134*64; i += 256) Ws[i] = W1[i];
    int sub = tid >> 6, lane = tid & 63;
    int node = blockIdx.x*4 + sub;
    if (node < N){
        fs[sub][2+lane]      = emb[node*128 + lane];
        fs[sub][2+64+lane]   = emb[node*128 + 64 + lane];
        if (lane < 2) fs[sub][lane]       = xc[node*2 + lane];
        if (lane < 4) fs[sub][130 + lane] = te[node*4 + lane];
    }
    __syncthreads();
    if (node < N){
        float acc = 0.f;
        #pragma unroll 2
        for (int k = 0; k < 134; k++) acc += fs[sub][k] * Ws[k*64 + lane];
        xw1[node*64 + lane] = acc;
    }
}

// ---------------- CSR gather, 64 channels: out1 = b1 + dis^2*xw1_self + sum ----------------
__global__ __launch_bounds__(256) void k_gather1(const int2* __restrict__ sorted, const int* __restrict__ base,
        const float* __restrict__ dis, const float* __restrict__ xw1, const float* __restrict__ b1,
        float* __restrict__ out1, int N){
    int node = blockIdx.x*4 + (threadIdx.x >> 6);
    int lane = threadIdx.x & 63;
    if (node >= N) return;
    int s = base[node], e_end = base[node+1];
    float d = dis[node];
    float acc = b1[lane] + d*d*xw1[(size_t)node*64 + lane];
    for (int e = s; e < e_end; e++){
        int2 pr = sorted[e];
        acc += __int_as_float(pr.y) * xw1[(size_t)pr.x*64 + lane];
    }
    out1[(size_t)node*64 + lane] = acc;
}

// ---------------- GCN layer 2: z1=relu(out1); xw2=z1@W2 ----------------
__global__ __launch_bounds__(256) void k_xw2(const float* __restrict__ out1, const float* __restrict__ W2,
        float* __restrict__ xw2, int N){
    __shared__ float Ws[64*128];
    __shared__ float zs[2][68];
    int tid = threadIdx.x;
    for (int i = tid; i < 64*128; i += 256) Ws[i] = W2[i];
    int sub = tid >> 7, lane = tid & 127;
    int node = blockIdx.x*2 + sub;
    if (node < N && lane < 64) zs[sub][lane] = fmaxf(out1[node*64 + lane], 0.f);
    __syncthreads();
    if (node < N){
        float acc = 0.f;
        #pragma unroll 4
        for (int k = 0; k < 64; k++) acc += zs[sub][k] * Ws[k*128 + lane];
        xw2[(size_t)node*128 + lane] = acc;
    }
}

// ---------------- CSR gather, 128 channels: z = b2 + dis^2*xw2_self + sum ----------------
__global__ __launch_bounds__(256) void k_gather2(const int2* __restrict__ sorted, const int* __restrict__ base,
        const float* __restrict__ dis, const float* __restrict__ xw2, const float* __restrict__ b2,
        float* __restrict__ z, int N){
    int node = blockIdx.x*2 + (threadIdx.x >> 7);
    int lane = threadIdx.x & 127;
    if (node >= N) return;
    int s = base[node], e_end = base[node+1];
    float d = dis[node];
    float acc = b2[lane] + d*d*xw2[(size_t)node*128 + lane];
    for (int e = s; e < e_end; e++){
        int2 pr = sorted[e];
        acc += __int_as_float(pr.y) * xw2[(size_t)pr.x*128 + lane];
    }
    z[(size_t)node*128 + lane] = acc;
}

// ---------------- build x = [z[seq] | dur_emb] ----------------
__global__ void k_build_x(const float* __restrict__ z, const int* __restrict__ seq,
        const float* __restrict__ dur, const float* __restrict__ dW1, const float* __restrict__ db1,
        const float* __restrict__ dW2, const float* __restrict__ db2, float* __restrict__ x){
    int row = blockIdx.x;
    int tid = threadIdx.x;       // 192 threads
    if (tid < 128){
        int node = seq[row];
        x[row*160 + tid] = z[node*128 + tid];
    } else if (tid < 160){
        int jj = tid - 128;
        float ld = log1pf(dur[row]);
        float acc = db2[jj];
        #pragma unroll
        for (int hh = 0; hh < 16; hh++){
            float hv = fmaxf(ld * dW1[hh] + db1[hh], 0.f);
            acc += hv * dW2[hh*32 + jj];
        }
        x[row*160 + tid] = acc;
    }
}

// ---------------- transpose Wih (512x160 -> 160x512), both dirs ----------------
__global__ void k_transpose_wih(const float* __restrict__ Wf, const float* __restrict__ Wb,
        float* __restrict__ Tf, float* __restrict__ Tb){
    int idx = blockIdx.x*256 + threadIdx.x;
    if (idx < 512*160){
        int g = idx / 160, k = idx % 160;
        Tf[k*512 + g] = Wf[idx];
        Tb[k*512 + g] = Wb[idx];
    }
}

// ---------------- generic f32 GEMM: C[M,N] = A[M,K] @ B[K,N] + bias[N] ----------------
#define MT 64
#define NT 128
#define KC 16
__global__ __launch_bounds__(256) void k_gemm(const float* __restrict__ A, const float* __restrict__ B,
        const float* __restrict__ bias, float* __restrict__ C, int M, int Nn, int K){
    __shared__ float As[KC][MT+4];
    __shared__ float Bs[KC][NT+4];
    int tid = threadIdx.x;
    int n0 = blockIdx.x * NT;
    int m0 = blockIdx.y * MT;
    int tn = tid & 31;
    int tm = tid >> 5;
    float acc[8][4];
    #pragma unroll
    for (int i = 0; i < 8; i++)
        #pragma unroll
        for (int j = 0; j < 4; j++) acc[i][j] = 0.f;

    for (int kt = 0; kt < K; kt += KC){
        {
            int m = tid >> 2, q = tid & 3;
            float4 a4 = *(const float4*)(A + (size_t)(m0+m)*K + kt + q*4);
            As[q*4+0][m] = a4.x; As[q*4+1][m] = a4.y; As[q*4+2][m] = a4.z; As[q*4+3][m] = a4.w;
        }
        {
            #pragma unroll
            for (int i = 0; i < 2; i++){
                int idx = tid*2 + i;
                int r = idx >> 5, c4 = idx & 31;
                int col = n0 + c4*4;
                float4 bv = make_float4(0.f,0.f,0.f,0.f);
                if (col < Nn) bv = *(const float4*)(B + (size_t)(kt+r)*Nn + col);
                *(float4*)(&Bs[r][c4*4]) = bv;
            }
        }
        __syncthreads();
        #pragma unroll
        for (int k = 0; k < KC; k++){
            float4 b4 = *(const float4*)(&Bs[k][tn*4]);
            float4 a0 = *(const float4*)(&As[k][tm*8]);
            float4 a1 = *(const float4*)(&As[k][tm*8+4]);
            float av[8] = {a0.x,a0.y,a0.z,a0.w,a1.x,a1.y,a1.z,a1.w};
            float bv[4] = {b4.x,b4.y,b4.z,b4.w};
            #pragma unroll
            for (int i = 0; i < 8; i++)
                #pragma unroll
                for (int j = 0; j < 4; j++) acc[i][j] += av[i]*bv[j];
        }
        __syncthreads();
    }
    int col = n0 + tn*4;
    if (col < Nn){
        float4 bb = *(const float4*)(bias + col);
        #pragma unroll
        for (int i = 0; i < 8; i++){
            int row = m0 + tm*8 + i;
            float4 o = make_float4(acc[i][0]+bb.x, acc[i][1]+bb.y, acc[i][2]+bb.z, acc[i][3]+bb.w);
            *(float4*)(C + (size_t)row*Nn + col) = o;
        }
    }
}

// ---------------- LSTM recurrence: one block per (batch row, direction) ----------------
__global__ __launch_bounds__(512) void k_lstm(const float* __restrict__ xg_f, const float* __restrict__ xg_b,
        const float* __restrict__ Whh_f, const float* __restrict__ Whh_b,
        const int* __restrict__ lengths, float* __restrict__ lstm_out, int T){
    int b = blockIdx.x;
    int dir = blockIdx.y;
    const float* xg  = dir ? xg_b  : xg_f;
    const float* Whh = dir ? Whh_b : Whh_f;
    int len = lengths[b];
    int j = threadIdx.x;
    __shared__ __align__(16) float h[128];
    __shared__ float g[512];
    float4 w[32];
    const float4* wrow = (const float4*)(Whh + j*128);
    #pragma unroll
    for (int k = 0; k < 32; k++) w[k] = wrow[k];
    if (j < 128) h[j] = 0.f;
    float c = 0.f;
    __syncthreads();
    for (int s = 0; s < len; s++){
        int t = dir ? (len-1-s) : s;
        float acc = xg[((size_t)b*T + t)*512 + j];
        const float4* h4 = (const float4*)h;
        #pragma unroll
        for (int k = 0; k < 32; k++){
            float4 hv = h4[k];
            acc += w[k].x*hv.x + w[k].y*hv.y + w[k].z*hv.z + w[k].w*hv.w;
        }
        g[j] = acc;
        __syncthreads();
        if (j < 128){
            float gi = g[j], gf = g[128+j], gg = g[256+j], go = g[384+j];
            float cn = sigmf(gf)*c + sigmf(gi)*tanh_f(gg);
            float hn = sigmf(go)*tanh_f(cn);
            c = cn;
            h[j] = hn;
            lstm_out[((size_t)b*T + t)*256 + dir*128 + j] = hn;
        }
        __syncthreads();
    }
}

// ---------------- attention + context ----------------
__global__ __launch_bounds__(256) void k_attn(const float* __restrict__ lstm_out,
        const float* __restrict__ attn_W, const int* __restrict__ lengths,
        float* __restrict__ context, int T){
    int b = blockIdx.x;
    int tid = threadIdx.x;
    int len = lengths[b];
    __shared__ float sc[TSEQ_MAX];
    __shared__ float red[8];
    int lane = tid & 63, wv = tid >> 6;
    float a0 = attn_W[lane], a1 = attn_W[64+lane], a2 = attn_W[128+lane], a3 = attn_W[192+lane];
    for (int t = wv; t < len; t += 4){
        const float* r = lstm_out + ((size_t)b*T + t)*256;
        float p = r[lane]*a0 + r[64+lane]*a1 + r[128+lane]*a2 + r[192+lane]*a3;
        #pragma unroll
        for (int o = 32; o > 0; o >>= 1) p += __shfl_down(p, o);
        if (lane == 0) sc[t] = p;
    }
    __syncthreads();
    float v = (tid < len) ? sc[tid] : -INFINITY;
    float m = v;
    #pragma unroll
    for (int o = 32; o > 0; o >>= 1) m = fmaxf(m, __shfl_down(m, o));
    if (lane == 0) red[wv] = m;
    __syncthreads();
    float M4 = fmaxf(fmaxf(red[0],red[1]), fmaxf(red[2],red[3]));
    float e = (tid < len) ? __expf(v - M4) : 0.f;
    float ss = e;
    #pragma unroll
    for (int o = 32; o > 0; o >>= 1) ss += __shfl_down(ss, o);
    if (lane == 0) red[4+wv] = ss;
    __syncthreads();
    float S = red[4]+red[5]+red[6]+red[7];
    sc[tid] = e / S;
    __syncthreads();
    float acc = 0.f;
    for (int t = 0; t < len; t++) acc += sc[t] * lstm_out[((size_t)b*T + t)*256 + tid];
    context[b*256 + tid] = acc;
}

extern "C" void kernel_launch(void* const* d_in, const int* in_sizes, int n_in,
                              void* d_out, int out_size, void* d_ws, size_t ws_size,
                              hipStream_t stream) {
    const float* x_coords  = (const float*)d_in[0];
    const float* temporal  = (const float*)d_in[1];
    const int*   edge_idx  = (const int*)  d_in[2];
    const float* edge_w    = (const float*)d_in[3];
    const int*   seq       = (const int*)  d_in[4];
    const float* durations = (const float*)d_in[5];
    const int*   lengths   = (const int*)  d_in[6];
    const float* node_emb  = (const float*)d_in[7];
    const float* gcn1_W    = (const float*)d_in[8];
    const float* gcn1_b    = (const float*)d_in[9];
    const float* gcn2_W    = (const float*)d_in[10];
    const float* gcn2_b    = (const float*)d_in[11];
    const float* dur_W1    = (const float*)d_in[12];
    const float* dur_b1    = (const float*)d_in[13];
    const float* dur_W2    = (const float*)d_in[14];
    const float* dur_b2    = (const float*)d_in[15];
    const float* Wih_f     = (const float*)d_in[16];
    const float* Whh_f     = (const float*)d_in[17];
    const float* b_f       = (const float*)d_in[18];
    const float* Wih_b     = (const float*)d_in[19];
    const float* Whh_b     = (const float*)d_in[20];
    const float* b_b       = (const float*)d_in[21];
    const float* attn_W    = (const float*)d_in[22];
    const float* fc_W      = (const float*)d_in[24];
    const float* fc_b      = (const float*)d_in[25];
    float* out = (float*)d_out;
    float* ws  = (float*)d_ws;

    const int N  = in_sizes[0] / 2;      // 100000
    const int E  = in_sizes[2] / 2;      // 1600000
    const int B  = in_sizes[6];          // 256
    const int T  = in_sizes[4] / B;      // 200
    const int BT = B * T;                // 51200

    // persistent region (floats)
    float* xg_f     = ws + 0;                       // 26,214,400
    float* xg_b     = ws + 26214400;                // 26,214,400
    float* xbuf     = ws + 52428800;                //  8,192,000
    float* lstm_out = ws + 60620800;                // 13,107,200
    float* context  = ws + 73728000;                //     65,536
    float* WihT_f   = ws + 73793536;                //     81,920
    float* WihT_b   = ws + 73875456;                //     81,920  (total ~296 MB)

    // GCN temporaries overlaid under xg region (all dead before GEMMs write xg)
    float* dis  = ws + 0;            // N
    float* xw1  = ws + 100352;       // N*64
    float* out1 = ws + 6500352;      // N*64
    float* xw2  = ws + 12900352;     // N*128
    float* zbuf = ws + 25700352;     // N*128  (ends 38,500,352)
    int2*  sorted   = (int2*)(ws + 38500352);   // E * 8B = 3.2M floats
    int*   cnt      = (int*) (ws + 41700352);   // N
    int*   base     = (int*) (ws + 41800352);   // N+1
    int*   cursor   = (int*) (ws + 41900356);   // N
    int*   partials = (int*) (ws + 42000356);   // 128

    const int SCAN_BLOCKS = (N + 1023) / 1024;  // 98

    // ---- GCN normalization ----
    k_deg_init<<<dim3((N+255)/256), dim3(256), 0, stream>>>(dis, N);
    k_deg_acc <<<dim3((E+255)/256), dim3(256), 0, stream>>>(edge_idx, edge_w, dis, E);
    k_dis     <<<dim3((N+255)/256), dim3(256), 0, stream>>>(dis, N);

    // ---- CSR build (sort edges by destination) ----
    hipMemsetAsync(cnt, 0, (size_t)N*sizeof(int), stream);
    k_count  <<<dim3((E+255)/256), dim3(256), 0, stream>>>(edge_idx, cnt, E);
    k_scan1  <<<dim3(SCAN_BLOCKS), dim3(256), 0, stream>>>(cnt, base, partials, N);
    k_scan2  <<<dim3(1), dim3(128), 0, stream>>>(partials, SCAN_BLOCKS);
    k_scan3  <<<dim3((N+256)/256), dim3(256), 0, stream>>>(base, cursor, partials, N, E);
    k_scatter<<<dim3((E+255)/256), dim3(256), 0, stream>>>(edge_idx, edge_w, dis, cursor, sorted, E);

    // ---- GCN layer 1 ----
    k_xw1    <<<dim3((N+3)/4), dim3(256), 0, stream>>>(x_coords, temporal, node_emb, gcn1_W, xw1, N);
    k_gather1<<<dim3((N+3)/4), dim3(256), 0, stream>>>(sorted, base, dis, xw1, gcn1_b, out1, N);

    // ---- GCN layer 2 ----
    k_xw2    <<<dim3((N+1)/2), dim3(256), 0, stream>>>(out1, gcn2_W, xw2, N);
    k_gather2<<<dim3((N+1)/2), dim3(256), 0, stream>>>(sorted, base, dis, xw2, gcn2_b, zbuf, N);

    // ---- sequence features ----
    k_build_x<<<dim3(BT), dim3(192), 0, stream>>>(zbuf, seq, durations, dur_W1, dur_b1, dur_W2, dur_b2, xbuf);

    // ---- input-gate GEMMs ----
    k_transpose_wih<<<dim3(320), dim3(256), 0, stream>>>(Wih_f, Wih_b, WihT_f, WihT_b);
    k_gemm<<<dim3(512/NT, BT/MT), dim3(256), 0, stream>>>(xbuf, WihT_f, b_f, xg_f, BT, 512, 160);
    k_gemm<<<dim3(512/NT, BT/MT), dim3(256), 0, stream>>>(xbuf, WihT_b, b_b, xg_b, BT, 512, 160);

    // ---- BiLSTM recurrence ----
    k_lstm<<<dim3(B, 2), dim3(512), 0, stream>>>(xg_f, xg_b, Whh_f, Whh_b, lengths, lstm_out, T);

    // ---- attention ----
    k_attn<<<dim3(B), dim3(256), 0, stream>>>(lstm_out, attn_W, lengths, context, T);

    // ---- final FC: (256 x 256) @ (256 x 100000) + fc_b ----
    k_gemm<<<dim3((N + NT - 1)/NT, B/MT), dim3(256), 0, stream>>>(context, fc_W, fc_b, out, B, N, 256);
}

// Round 3
// 1939.137 us; speedup vs baseline: 1.2990x; 1.0285x over previous
//
#include <hip/hip_runtime.h>
#include <math.h>

#define TSEQ_MAX 256

__device__ __forceinline__ float sigmf(float x){ return 1.f/(1.f+__expf(-x)); }
__device__ __forceinline__ float tanh_f(float x){ return 1.f - 2.f/(__expf(2.f*x)+1.f); }

// ---------------- GCN degree / norm ----------------
__global__ void k_deg_init(float* deg, int N){
    int i = blockIdx.x*256 + threadIdx.x;
    if (i < N) deg[i] = 1.0f;              // self-loop weight
}
__global__ void k_deg_acc(const int* __restrict__ ei, const float* __restrict__ ew, float* deg, int E){
    int e = blockIdx.x*256 + threadIdx.x;
    if (e < E) atomicAdd(&deg[ei[E + e]], ew[e]);
}
__global__ void k_dis(float* deg, int N){
    int i = blockIdx.x*256 + threadIdx.x;
    if (i < N){ float d = deg[i]; deg[i] = (d > 0.f) ? rsqrtf(fmaxf(d, 1e-12f)) : 0.f; }
}

// ---------------- CSR build: count, scan, scatter ----------------
__global__ void k_count(const int* __restrict__ ei, int* __restrict__ cnt, int E){
    int e = blockIdx.x*256 + threadIdx.x;
    if (e < E) atomicAdd(&cnt[ei[E + e]], 1);
}

__global__ __launch_bounds__(256) void k_scan1(const int* __restrict__ cnt, int* __restrict__ base,
        int* __restrict__ partials, int N){
    __shared__ int sh[256];
    int tid = threadIdx.x;
    int i0 = blockIdx.x*1024 + tid*4;
    int v0=0,v1=0,v2=0,v3=0;
    if (i0+0 < N) v0 = cnt[i0+0];
    if (i0+1 < N) v1 = cnt[i0+1];
    if (i0+2 < N) v2 = cnt[i0+2];
    if (i0+3 < N) v3 = cnt[i0+3];
    int tsum = v0+v1+v2+v3;
    sh[tid] = tsum;
    __syncthreads();
    for (int off = 1; off < 256; off <<= 1){
        int val = (tid >= off) ? sh[tid-off] : 0;
        __syncthreads();
        sh[tid] += val;
        __syncthreads();
    }
    int excl = sh[tid] - tsum;
    if (i0+0 < N) base[i0+0] = excl;
    if (i0+1 < N) base[i0+1] = excl + v0;
    if (i0+2 < N) base[i0+2] = excl + v0 + v1;
    if (i0+3 < N) base[i0+3] = excl + v0 + v1 + v2;
    if (tid == 255) partials[blockIdx.x] = sh[255];
}
__global__ __launch_bounds__(128) void k_scan2(int* partials, int nb){
    __shared__ int sh[128];
    int tid = threadIdx.x;
    int v = (tid < nb) ? partials[tid] : 0;
    sh[tid] = v;
    __syncthreads();
    for (int off = 1; off < 128; off <<= 1){
        int val = (tid >= off) ? sh[tid-off] : 0;
        __syncthreads();
        sh[tid] += val;
        __syncthreads();
    }
    if (tid < nb) partials[tid] = sh[tid] - v;   // exclusive
}
__global__ void k_scan3(int* base, int* cursor, const int* __restrict__ partials, int N, int E){
    int i = blockIdx.x*256 + threadIdx.x;
    if (i < N){
        int v = base[i] + partials[i >> 10];
        base[i] = v; cursor[i] = v;
    }
    if (i == N) base[N] = E;
}
__global__ void k_scatter(const int* __restrict__ ei, const float* __restrict__ ew,
        const float* __restrict__ dis, int* cursor, int2* __restrict__ sorted, int E){
    int e = blockIdx.x*256 + threadIdx.x;
    if (e < E){
        int r = ei[e], c = ei[E + e];
        float nrm = dis[r] * ew[e] * dis[c];
        int pos = atomicAdd(&cursor[c], 1);
        sorted[pos] = make_int2(r, __float_as_int(nrm));
    }
}

// ---------------- GCN layer 1: xw1 = feats@W1 ----------------
__global__ __launch_bounds__(256) void k_xw1(const float* __restrict__ xc, const float* __restrict__ te,
        const float* __restrict__ emb, const float* __restrict__ W1,
        float* __restrict__ xw1, int N){
    __shared__ float Ws[134*64];
    __shared__ float fs[4][136];
    int tid = threadIdx.x;
    for (int i = tid; i < 134*64; i += 256) Ws[i] = W1[i];
    int sub = tid >> 6, lane = tid & 63;
    int node = blockIdx.x*4 + sub;
    if (node < N){
        fs[sub][2+lane]      = emb[node*128 + lane];
        fs[sub][2+64+lane]   = emb[node*128 + 64 + lane];
        if (lane < 2) fs[sub][lane]       = xc[node*2 + lane];
        if (lane < 4) fs[sub][130 + lane] = te[node*4 + lane];
    }
    __syncthreads();
    if (node < N){
        float acc = 0.f;
        #pragma unroll 2
        for (int k = 0; k < 134; k++) acc += fs[sub][k] * Ws[k*64 + lane];
        xw1[node*64 + lane] = acc;
    }
}

// ---------------- CSR gather, 64 channels ----------------
__global__ __launch_bounds__(256) void k_gather1(const int2* __restrict__ sorted, const int* __restrict__ base,
        const float* __restrict__ dis, const float* __restrict__ xw1, const float* __restrict__ b1,
        float* __restrict__ out1, int N){
    int node = blockIdx.x*4 + (threadIdx.x >> 6);
    int lane = threadIdx.x & 63;
    if (node >= N) return;
    int s = base[node], e_end = base[node+1];
    float d = dis[node];
    float acc = b1[lane] + d*d*xw1[(size_t)node*64 + lane];
    for (int e = s; e < e_end; e++){
        int2 pr = sorted[e];
        acc += __int_as_float(pr.y) * xw1[(size_t)pr.x*64 + lane];
    }
    out1[(size_t)node*64 + lane] = acc;
}

// ---------------- GCN layer 2: z1=relu(out1); xw2=z1@W2 ----------------
__global__ __launch_bounds__(256) void k_xw2(const float* __restrict__ out1, const float* __restrict__ W2,
        float* __restrict__ xw2, int N){
    __shared__ float Ws[64*128];
    __shared__ float zs[2][68];
    int tid = threadIdx.x;
    for (int i = tid; i < 64*128; i += 256) Ws[i] = W2[i];
    int sub = tid >> 7, lane = tid & 127;
    int node = blockIdx.x*2 + sub;
    if (node < N && lane < 64) zs[sub][lane] = fmaxf(out1[node*64 + lane], 0.f);
    __syncthreads();
    if (node < N){
        float acc = 0.f;
        #pragma unroll 4
        for (int k = 0; k < 64; k++) acc += zs[sub][k] * Ws[k*128 + lane];
        xw2[(size_t)node*128 + lane] = acc;
    }
}

// ---------------- CSR gather, 128 channels ----------------
__global__ __launch_bounds__(256) void k_gather2(const int2* __restrict__ sorted, const int* __restrict__ base,
        const float* __restrict__ dis, const float* __restrict__ xw2, const float* __restrict__ b2,
        float* __restrict__ z, int N){
    int node = blockIdx.x*2 + (threadIdx.x >> 7);
    int lane = threadIdx.x & 127;
    if (node >= N) return;
    int s = base[node], e_end = base[node+1];
    float d = dis[node];
    float acc = b2[lane] + d*d*xw2[(size_t)node*128 + lane];
    for (int e = s; e < e_end; e++){
        int2 pr = sorted[e];
        acc += __int_as_float(pr.y) * xw2[(size_t)pr.x*128 + lane];
    }
    z[(size_t)node*128 + lane] = acc;
}

// ---------------- build x = [z[seq] | dur_emb] ----------------
__global__ void k_build_x(const float* __restrict__ z, const int* __restrict__ seq,
        const float* __restrict__ dur, const float* __restrict__ dW1, const float* __restrict__ db1,
        const float* __restrict__ dW2, const float* __restrict__ db2, float* __restrict__ x){
    int row = blockIdx.x;
    int tid = threadIdx.x;       // 192 threads
    if (tid < 128){
        int node = seq[row];
        x[row*160 + tid] = z[node*128 + tid];
    } else if (tid < 160){
        int jj = tid - 128;
        float ld = log1pf(dur[row]);
        float acc = db2[jj];
        #pragma unroll
        for (int hh = 0; hh < 16; hh++){
            float hv = fmaxf(ld * dW1[hh] + db1[hh], 0.f);
            acc += hv * dW2[hh*32 + jj];
        }
        x[row*160 + tid] = acc;
    }
}

// ---------------- transpose Wih (512x160 -> 160x512), both dirs ----------------
__global__ void k_transpose_wih(const float* __restrict__ Wf, const float* __restrict__ Wb,
        float* __restrict__ Tf, float* __restrict__ Tb){
    int idx = blockIdx.x*256 + threadIdx.x;
    if (idx < 512*160){
        int g = idx / 160, k = idx % 160;
        Tf[k*512 + g] = Wf[idx];
        Tb[k*512 + g] = Wb[idx];
    }
}

// ---------------- generic f32 GEMM: C[M,N] = A[M,K] @ B[K,N] + bias[N] ----------------
#define MT 64
#define NT 128
#define KC 16
__global__ __launch_bounds__(256) void k_gemm(const float* __restrict__ A, const float* __restrict__ B,
        const float* __restrict__ bias, float* __restrict__ C, int M, int Nn, int K){
    __shared__ float As[KC][MT+4];
    __shared__ float Bs[KC][NT+4];
    int tid = threadIdx.x;
    int n0 = blockIdx.x * NT;
    int m0 = blockIdx.y * MT;
    int tn = tid & 31;
    int tm = tid >> 5;
    float acc[8][4];
    #pragma unroll
    for (int i = 0; i < 8; i++)
        #pragma unroll
        for (int j = 0; j < 4; j++) acc[i][j] = 0.f;

    for (int kt = 0; kt < K; kt += KC){
        {
            int m = tid >> 2, q = tid & 3;
            float4 a4 = *(const float4*)(A + (size_t)(m0+m)*K + kt + q*4);
            As[q*4+0][m] = a4.x; As[q*4+1][m] = a4.y; As[q*4+2][m] = a4.z; As[q*4+3][m] = a4.w;
        }
        {
            #pragma unroll
            for (int i = 0; i < 2; i++){
                int idx = tid*2 + i;
                int r = idx >> 5, c4 = idx & 31;
                int col = n0 + c4*4;
                float4 bv = make_float4(0.f,0.f,0.f,0.f);
                if (col < Nn) bv = *(const float4*)(B + (size_t)(kt+r)*Nn + col);
                *(float4*)(&Bs[r][c4*4]) = bv;
            }
        }
        __syncthreads();
        #pragma unroll
        for (int k = 0; k < KC; k++){
            float4 b4 = *(const float4*)(&Bs[k][tn*4]);
            float4 a0 = *(const float4*)(&As[k][tm*8]);
            float4 a1 = *(const float4*)(&As[k][tm*8+4]);
            float av[8] = {a0.x,a0.y,a0.z,a0.w,a1.x,a1.y,a1.z,a1.w};
            float bv[4] = {b4.x,b4.y,b4.z,b4.w};
            #pragma unroll
            for (int i = 0; i < 8; i++)
                #pragma unroll
                for (int j = 0; j < 4; j++) acc[i][j] += av[i]*bv[j];
        }
        __syncthreads();
    }
    int col = n0 + tn*4;
    if (col < Nn){
        float4 bb = *(const float4*)(bias + col);
        #pragma unroll
        for (int i = 0; i < 8; i++){
            int row = m0 + tm*8 + i;
            float4 o = make_float4(acc[i][0]+bb.x, acc[i][1]+bb.y, acc[i][2]+bb.z, acc[i][3]+bb.w);
            *(float4*)(C + (size_t)row*Nn + col) = o;
        }
    }
}

// ---------------- job sort: order (row,dir) jobs by descending length (LPT) ----------------
__global__ __launch_bounds__(512) void k_sortjobs(const int* __restrict__ lengths,
        int* __restrict__ jobs, int* __restrict__ counter){
    __shared__ int keys[512];
    __shared__ int vals[512];
    int tid = threadIdx.x;
    keys[tid] = -lengths[tid >> 1];     // ascending sort of -len == descending len
    vals[tid] = tid;
    __syncthreads();
    for (int k = 2; k <= 512; k <<= 1){
        for (int jj = k >> 1; jj > 0; jj >>= 1){
            int ixj = tid ^ jj;
            if (ixj > tid){
                bool up = ((tid & k) == 0);
                int k0 = keys[tid], k1 = keys[ixj];
                if ((k0 > k1) == up){
                    keys[tid] = k1; keys[ixj] = k0;
                    int v0 = vals[tid]; vals[tid] = vals[ixj]; vals[ixj] = v0;
                }
            }
            __syncthreads();
        }
    }
    jobs[tid] = vals[tid];
    if (tid == 0) *counter = 0;
}

// ---------------- LSTM recurrence: one block per job = (batch row, direction) ----------------
// __launch_bounds__(512, 2): VGPR cap 256 so the full Whh row (128 f32) stays in
// registers — at the default cap (88 VGPR) the compiler spilled ~40 floats to
// scratch and re-read them every timestep (458 us dispatch).
__global__ __launch_bounds__(512, 2) void k_lstm(const float* __restrict__ xg_f, const float* __restrict__ xg_b,
        const float* __restrict__ Whh_f, const float* __restrict__ Whh_b,
        const int* __restrict__ lengths, const int* __restrict__ jobs, int* __restrict__ counter,
        float* __restrict__ lstm_out, int T){
    __shared__ int job_s;
    int j = threadIdx.x;
    if (j == 0) job_s = atomicAdd(counter, 1);
    __syncthreads();
    int job = jobs[job_s];
    int b = job >> 1, dir = job & 1;
    const float* xg  = dir ? xg_b  : xg_f;
    const float* Whh = dir ? Whh_b : Whh_f;
    int len = lengths[b];
    __shared__ __align__(16) float h[128];
    __shared__ float g[512];
    float4 w[32];
    const float4* wrow = (const float4*)(Whh + j*128);
    #pragma unroll
    for (int k = 0; k < 32; k++) w[k] = wrow[k];
    if (j < 128) h[j] = 0.f;
    float c = 0.f;
    const float* xgb = xg + (size_t)b*T*512 + j;
    float* lob = lstm_out + (size_t)b*T*256 + dir*128 + j;
    int t0 = dir ? (len-1) : 0;
    float xg_next = xgb[(size_t)t0*512];
    __syncthreads();
    for (int s = 0; s < len; s++){
        int t = dir ? (len-1-s) : s;
        float xgv = xg_next;
        if (s+1 < len){
            int tn = dir ? (len-2-s) : (s+1);
            xg_next = xgb[(size_t)tn*512];      // prefetch next step's gate input
        }
        const float4* h4 = (const float4*)h;
        float p0=0.f, p1=0.f, p2=0.f, p3=0.f;   // 4 chains: dep depth 32 not 128
        #pragma unroll
        for (int k = 0; k < 32; k += 4){
            float4 ha = h4[k+0]; p0 += w[k+0].x*ha.x + w[k+0].y*ha.y + w[k+0].z*ha.z + w[k+0].w*ha.w;
            float4 hb = h4[k+1]; p1 += w[k+1].x*hb.x + w[k+1].y*hb.y + w[k+1].z*hb.z + w[k+1].w*hb.w;
            float4 hc = h4[k+2]; p2 += w[k+2].x*hc.x + w[k+2].y*hc.y + w[k+2].z*hc.z + w[k+2].w*hc.w;
            float4 hd = h4[k+3]; p3 += w[k+3].x*hd.x + w[k+3].y*hd.y + w[k+3].z*hd.z + w[k+3].w*hd.w;
        }
        g[j] = xgv + ((p0+p1)+(p2+p3));
        __syncthreads();
        if (j < 128){
            float gi = g[j], gf = g[128+j], gg = g[256+j], go = g[384+j];
            float cn = sigmf(gf)*c + sigmf(gi)*tanh_f(gg);
            float hn = sigmf(go)*tanh_f(cn);
            c = cn;
            h[j] = hn;
            lob[(size_t)t*256] = hn;
        }
        __syncthreads();
    }
}

// ---------------- attention + context ----------------
__global__ __launch_bounds__(256) void k_attn(const float* __restrict__ lstm_out,
        const float* __restrict__ attn_W, const int* __restrict__ lengths,
        float* __restrict__ context, int T){
    int b = blockIdx.x;
    int tid = threadIdx.x;
    int len = lengths[b];
    __shared__ float sc[TSEQ_MAX];
    __shared__ float red[8];
    int lane = tid & 63, wv = tid >> 6;
    float a0 = attn_W[lane], a1 = attn_W[64+lane], a2 = attn_W[128+lane], a3 = attn_W[192+lane];
    for (int t = wv; t < len; t += 4){
        const float* r = lstm_out + ((size_t)b*T + t)*256;
        float p = r[lane]*a0 + r[64+lane]*a1 + r[128+lane]*a2 + r[192+lane]*a3;
        #pragma unroll
        for (int o = 32; o > 0; o >>= 1) p += __shfl_down(p, o);
        if (lane == 0) sc[t] = p;
    }
    __syncthreads();
    float v = (tid < len) ? sc[tid] : -INFINITY;
    float m = v;
    #pragma unroll
    for (int o = 32; o > 0; o >>= 1) m = fmaxf(m, __shfl_down(m, o));
    if (lane == 0) red[wv] = m;
    __syncthreads();
    float M4 = fmaxf(fmaxf(red[0],red[1]), fmaxf(red[2],red[3]));
    float e = (tid < len) ? __expf(v - M4) : 0.f;
    float ss = e;
    #pragma unroll
    for (int o = 32; o > 0; o >>= 1) ss += __shfl_down(ss, o);
    if (lane == 0) red[4+wv] = ss;
    __syncthreads();
    float S = red[4]+red[5]+red[6]+red[7];
    sc[tid] = e / S;
    __syncthreads();
    float acc = 0.f;
    for (int t = 0; t < len; t++) acc += sc[t] * lstm_out[((size_t)b*T + t)*256 + tid];
    context[b*256 + tid] = acc;
}

extern "C" void kernel_launch(void* const* d_in, const int* in_sizes, int n_in,
                              void* d_out, int out_size, void* d_ws, size_t ws_size,
                              hipStream_t stream) {
    const float* x_coords  = (const float*)d_in[0];
    const float* temporal  = (const float*)d_in[1];
    const int*   edge_idx  = (const int*)  d_in[2];
    const float* edge_w    = (const float*)d_in[3];
    const int*   seq       = (const int*)  d_in[4];
    const float* durations = (const float*)d_in[5];
    const int*   lengths   = (const int*)  d_in[6];
    const float* node_emb  = (const float*)d_in[7];
    const float* gcn1_W    = (const float*)d_in[8];
    const float* gcn1_b    = (const float*)d_in[9];
    const float* gcn2_W    = (const float*)d_in[10];
    const float* gcn2_b    = (const float*)d_in[11];
    const float* dur_W1    = (const float*)d_in[12];
    const float* dur_b1    = (const float*)d_in[13];
    const float* dur_W2    = (const float*)d_in[14];
    const float* dur_b2    = (const float*)d_in[15];
    const float* Wih_f     = (const float*)d_in[16];
    const float* Whh_f     = (const float*)d_in[17];
    const float* b_f       = (const float*)d_in[18];
    const float* Wih_b     = (const float*)d_in[19];
    const float* Whh_b     = (const float*)d_in[20];
    const float* b_b       = (const float*)d_in[21];
    const float* attn_W    = (const float*)d_in[22];
    const float* fc_W      = (const float*)d_in[24];
    const float* fc_b      = (const float*)d_in[25];
    float* out = (float*)d_out;
    float* ws  = (float*)d_ws;

    const int N  = in_sizes[0] / 2;      // 100000
    const int E  = in_sizes[2] / 2;      // 1600000
    const int B  = in_sizes[6];          // 256
    const int T  = in_sizes[4] / B;      // 200
    const int BT = B * T;                // 51200

    // persistent region (floats)
    float* xg_f     = ws + 0;                       // 26,214,400
    float* xg_b     = ws + 26214400;                // 26,214,400
    float* xbuf     = ws + 52428800;                //  8,192,000
    float* lstm_out = ws + 60620800;                // 13,107,200
    float* context  = ws + 73728000;                //     65,536
    float* WihT_f   = ws + 73793536;                //     81,920
    float* WihT_b   = ws + 73875456;                //     81,920  (total ~296 MB)

    // jobs/counter live in the context region: written by k_sortjobs early,
    // consumed by k_lstm, dead before k_attn writes context.
    int* jobs    = (int*)context;          // 512 ints
    int* counter = (int*)context + 512;    // 1 int

    // GCN temporaries overlaid under xg region (all dead before GEMMs write xg)
    float* dis  = ws + 0;            // N
    float* xw1  = ws + 100352;       // N*64
    float* out1 = ws + 6500352;      // N*64
    float* xw2  = ws + 12900352;     // N*128
    float* zbuf = ws + 25700352;     // N*128  (ends 38,500,352)
    int2*  sorted   = (int2*)(ws + 38500352);   // E * 8B
    int*   cnt      = (int*) (ws + 41700352);   // N
    int*   base     = (int*) (ws + 41800352);   // N+1
    int*   cursor   = (int*) (ws + 41900356);   // N
    int*   partials = (int*) (ws + 42000356);   // 128

    const int SCAN_BLOCKS = (N + 1023) / 1024;  // 98

    // ---- job ordering for LSTM load balance ----
    k_sortjobs<<<dim3(1), dim3(512), 0, stream>>>(lengths, jobs, counter);

    // ---- GCN normalization ----
    k_deg_init<<<dim3((N+255)/256), dim3(256), 0, stream>>>(dis, N);
    k_deg_acc <<<dim3((E+255)/256), dim3(256), 0, stream>>>(edge_idx, edge_w, dis, E);
    k_dis     <<<dim3((N+255)/256), dim3(256), 0, stream>>>(dis, N);

    // ---- CSR build (sort edges by destination) ----
    hipMemsetAsync(cnt, 0, (size_t)N*sizeof(int), stream);
    k_count  <<<dim3((E+255)/256), dim3(256), 0, stream>>>(edge_idx, cnt, E);
    k_scan1  <<<dim3(SCAN_BLOCKS), dim3(256), 0, stream>>>(cnt, base, partials, N);
    k_scan2  <<<dim3(1), dim3(128), 0, stream>>>(partials, SCAN_BLOCKS);
    k_scan3  <<<dim3((N+256)/256), dim3(256), 0, stream>>>(base, cursor, partials, N, E);
    k_scatter<<<dim3((E+255)/256), dim3(256), 0, stream>>>(edge_idx, edge_w, dis, cursor, sorted, E);

    // ---- GCN layer 1 ----
    k_xw1    <<<dim3((N+3)/4), dim3(256), 0, stream>>>(x_coords, temporal, node_emb, gcn1_W, xw1, N);
    k_gather1<<<dim3((N+3)/4), dim3(256), 0, stream>>>(sorted, base, dis, xw1, gcn1_b, out1, N);

    // ---- GCN layer 2 ----
    k_xw2    <<<dim3((N+1)/2), dim3(256), 0, stream>>>(out1, gcn2_W, xw2, N);
    k_gather2<<<dim3((N+1)/2), dim3(256), 0, stream>>>(sorted, base, dis, xw2, gcn2_b, zbuf, N);

    // ---- sequence features ----
    k_build_x<<<dim3(BT), dim3(192), 0, stream>>>(zbuf, seq, durations, dur_W1, dur_b1, dur_W2, dur_b2, xbuf);

    // ---- input-gate GEMMs ----
    k_transpose_wih<<<dim3(320), dim3(256), 0, stream>>>(Wih_f, Wih_b, WihT_f, WihT_b);
    k_gemm<<<dim3(512/NT, BT/MT), dim3(256), 0, stream>>>(xbuf, WihT_f, b_f, xg_f, BT, 512, 160);
    k_gemm<<<dim3(512/NT, BT/MT), dim3(256), 0, stream>>>(xbuf, WihT_b, b_b, xg_b, BT, 512, 160);

    // ---- BiLSTM recurrence (LPT job order) ----
    k_lstm<<<dim3(2*B), dim3(512), 0, stream>>>(xg_f, xg_b, Whh_f, Whh_b, lengths, jobs, counter, lstm_out, T);

    // ---- attention ----
    k_attn<<<dim3(B), dim3(256), 0, stream>>>(lstm_out, attn_W, lengths, context, T);

    // ---- final FC: (256 x 256) @ (256 x 100000) + fc_b ----
    k_gemm<<<dim3((N + NT - 1)/NT, B/MT), dim3(256), 0, stream>>>(context, fc_W, fc_b, out, B, N, 256);
}

// Round 4
// 1846.569 us; speedup vs baseline: 1.3641x; 1.0501x over previous
//
#include <hip/hip_runtime.h>
#include <math.h>

#define TSEQ_MAX 256

typedef float v2f __attribute__((ext_vector_type(2)));

__device__ __forceinline__ float sigmf(float x){ return 1.f/(1.f+__expf(-x)); }
__device__ __forceinline__ float tanh_f(float x){ return 1.f - 2.f/(__expf(2.f*x)+1.f); }

// ---------------- GCN degree / norm ----------------
__global__ void k_deg_init(float* deg, int N){
    int i = blockIdx.x*256 + threadIdx.x;
    if (i < N) deg[i] = 1.0f;              // self-loop weight
}
__global__ void k_deg_acc(const int* __restrict__ ei, const float* __restrict__ ew, float* deg, int E){
    int e = blockIdx.x*256 + threadIdx.x;
    if (e < E) atomicAdd(&deg[ei[E + e]], ew[e]);
}
__global__ void k_dis(float* deg, int N){
    int i = blockIdx.x*256 + threadIdx.x;
    if (i < N){ float d = deg[i]; deg[i] = (d > 0.f) ? rsqrtf(fmaxf(d, 1e-12f)) : 0.f; }
}

// ---------------- CSR build: count, scan, scatter ----------------
__global__ void k_count(const int* __restrict__ ei, int* __restrict__ cnt, int E){
    int e = blockIdx.x*256 + threadIdx.x;
    if (e < E) atomicAdd(&cnt[ei[E + e]], 1);
}

__global__ __launch_bounds__(256) void k_scan1(const int* __restrict__ cnt, int* __restrict__ base,
        int* __restrict__ partials, int N){
    __shared__ int sh[256];
    int tid = threadIdx.x;
    int i0 = blockIdx.x*1024 + tid*4;
    int v0=0,v1=0,v2=0,v3=0;
    if (i0+0 < N) v0 = cnt[i0+0];
    if (i0+1 < N) v1 = cnt[i0+1];
    if (i0+2 < N) v2 = cnt[i0+2];
    if (i0+3 < N) v3 = cnt[i0+3];
    int tsum = v0+v1+v2+v3;
    sh[tid] = tsum;
    __syncthreads();
    for (int off = 1; off < 256; off <<= 1){
        int val = (tid >= off) ? sh[tid-off] : 0;
        __syncthreads();
        sh[tid] += val;
        __syncthreads();
    }
    int excl = sh[tid] - tsum;
    if (i0+0 < N) base[i0+0] = excl;
    if (i0+1 < N) base[i0+1] = excl + v0;
    if (i0+2 < N) base[i0+2] = excl + v0 + v1;
    if (i0+3 < N) base[i0+3] = excl + v0 + v1 + v2;
    if (tid == 255) partials[blockIdx.x] = sh[255];
}
__global__ __launch_bounds__(128) void k_scan2(int* partials, int nb){
    __shared__ int sh[128];
    int tid = threadIdx.x;
    int v = (tid < nb) ? partials[tid] : 0;
    sh[tid] = v;
    __syncthreads();
    for (int off = 1; off < 128; off <<= 1){
        int val = (tid >= off) ? sh[tid-off] : 0;
        __syncthreads();
        sh[tid] += val;
        __syncthreads();
    }
    if (tid < nb) partials[tid] = sh[tid] - v;   // exclusive
}
__global__ void k_scan3(int* base, int* cursor, const int* __restrict__ partials, int N, int E){
    int i = blockIdx.x*256 + threadIdx.x;
    if (i < N){
        int v = base[i] + partials[i >> 10];
        base[i] = v; cursor[i] = v;
    }
    if (i == N) base[N] = E;
}
__global__ void k_scatter(const int* __restrict__ ei, const float* __restrict__ ew,
        const float* __restrict__ dis, int* cursor, int2* __restrict__ sorted, int E){
    int e = blockIdx.x*256 + threadIdx.x;
    if (e < E){
        int r = ei[e], c = ei[E + e];
        float nrm = dis[r] * ew[e] * dis[c];
        int pos = atomicAdd(&cursor[c], 1);
        sorted[pos] = make_int2(r, __float_as_int(nrm));
    }
}

// ---------------- GCN layer 1: xw1 = feats@W1 ----------------
__global__ __launch_bounds__(256) void k_xw1(const float* __restrict__ xc, const float* __restrict__ te,
        const float* __restrict__ emb, const float* __restrict__ W1,
        float* __restrict__ xw1, int N){
    __shared__ float Ws[134*64];
    __shared__ float fs[4][136];
    int tid = threadIdx.x;
    for (int i = tid; i < 134*64; i += 256) Ws[i] = W1[i];
    int sub = tid >> 6, lane = tid & 63;
    int node = blockIdx.x*4 + sub;
    if (node < N){
        fs[sub][2+lane]      = emb[node*128 + lane];
        fs[sub][2+64+lane]   = emb[node*128 + 64 + lane];
        if (lane < 2) fs[sub][lane]       = xc[node*2 + lane];
        if (lane < 4) fs[sub][130 + lane] = te[node*4 + lane];
    }
    __syncthreads();
    if (node < N){
        float acc = 0.f;
        #pragma unroll 2
        for (int k = 0; k < 134; k++) acc += fs[sub][k] * Ws[k*64 + lane];
        xw1[node*64 + lane] = acc;
    }
}

// ---------------- CSR gather, 64 channels ----------------
__global__ __launch_bounds__(256) void k_gather1(const int2* __restrict__ sorted, const int* __restrict__ base,
        const float* __restrict__ dis, const float* __restrict__ xw1, const float* __restrict__ b1,
        float* __restrict__ out1, int N){
    int node = blockIdx.x*4 + (threadIdx.x >> 6);
    int lane = threadIdx.x & 63;
    if (node >= N) return;
    int s = base[node], e_end = base[node+1];
    float d = dis[node];
    float acc = b1[lane] + d*d*xw1[(size_t)node*64 + lane];
    for (int e = s; e < e_end; e++){
        int2 pr = sorted[e];
        acc += __int_as_float(pr.y) * xw1[(size_t)pr.x*64 + lane];
    }
    out1[(size_t)node*64 + lane] = acc;
}

// ---------------- GCN layer 2: z1=relu(out1); xw2=z1@W2 ----------------
__global__ __launch_bounds__(256) void k_xw2(const float* __restrict__ out1, const float* __restrict__ W2,
        float* __restrict__ xw2, int N){
    __shared__ float Ws[64*128];
    __shared__ float zs[2][68];
    int tid = threadIdx.x;
    for (int i = tid; i < 64*128; i += 256) Ws[i] = W2[i];
    int sub = tid >> 7, lane = tid & 127;
    int node = blockIdx.x*2 + sub;
    if (node < N && lane < 64) zs[sub][lane] = fmaxf(out1[node*64 + lane], 0.f);
    __syncthreads();
    if (node < N){
        float acc = 0.f;
        #pragma unroll 4
        for (int k = 0; k < 64; k++) acc += zs[sub][k] * Ws[k*128 + lane];
        xw2[(size_t)node*128 + lane] = acc;
    }
}

// ---------------- CSR gather, 128 channels ----------------
__global__ __launch_bounds__(256) void k_gather2(const int2* __restrict__ sorted, const int* __restrict__ base,
        const float* __restrict__ dis, const float* __restrict__ xw2, const float* __restrict__ b2,
        float* __restrict__ z, int N){
    int node = blockIdx.x*2 + (threadIdx.x >> 7);
    int lane = threadIdx.x & 127;
    if (node >= N) return;
    int s = base[node], e_end = base[node+1];
    float d = dis[node];
    float acc = b2[lane] + d*d*xw2[(size_t)node*128 + lane];
    for (int e = s; e < e_end; e++){
        int2 pr = sorted[e];
        acc += __int_as_float(pr.y) * xw2[(size_t)pr.x*128 + lane];
    }
    z[(size_t)node*128 + lane] = acc;
}

// ---------------- build x = [z[seq] | dur_emb] ----------------
__global__ void k_build_x(const float* __restrict__ z, const int* __restrict__ seq,
        const float* __restrict__ dur, const float* __restrict__ dW1, const float* __restrict__ db1,
        const float* __restrict__ dW2, const float* __restrict__ db2, float* __restrict__ x){
    int row = blockIdx.x;
    int tid = threadIdx.x;       // 192 threads
    if (tid < 128){
        int node = seq[row];
        x[row*160 + tid] = z[node*128 + tid];
    } else if (tid < 160){
        int jj = tid - 128;
        float ld = log1pf(dur[row]);
        float acc = db2[jj];
        #pragma unroll
        for (int hh = 0; hh < 16; hh++){
            float hv = fmaxf(ld * dW1[hh] + db1[hh], 0.f);
            acc += hv * dW2[hh*32 + jj];
        }
        x[row*160 + tid] = acc;
    }
}

// ---------------- transpose Wih (512x160 -> 160x512), both dirs ----------------
__global__ void k_transpose_wih(const float* __restrict__ Wf, const float* __restrict__ Wb,
        float* __restrict__ Tf, float* __restrict__ Tb){
    int idx = blockIdx.x*256 + threadIdx.x;
    if (idx < 512*160){
        int g = idx / 160, k = idx % 160;
        Tf[k*512 + g] = Wf[idx];
        Tb[k*512 + g] = Wb[idx];
    }
}

// ---------------- generic f32 GEMM: C[M,N] = A[M,K] @ B[K,N] + bias[N] ----------------
#define MT 64
#define NT 128
#define KC 16
__global__ __launch_bounds__(256) void k_gemm(const float* __restrict__ A, const float* __restrict__ B,
        const float* __restrict__ bias, float* __restrict__ C, int M, int Nn, int K){
    __shared__ float As[KC][MT+4];
    __shared__ float Bs[KC][NT+4];
    int tid = threadIdx.x;
    int n0 = blockIdx.x * NT;
    int m0 = blockIdx.y * MT;
    int tn = tid & 31;
    int tm = tid >> 5;
    v2f acc[8][2];                       // packed fp32 pairs -> v_pk_fma_f32
    #pragma unroll
    for (int i = 0; i < 8; i++){ acc[i][0] = (v2f){0.f,0.f}; acc[i][1] = (v2f){0.f,0.f}; }

    for (int kt = 0; kt < K; kt += KC){
        {
            int m = tid >> 2, q = tid & 3;
            float4 a4 = *(const float4*)(A + (size_t)(m0+m)*K + kt + q*4);
            As[q*4+0][m] = a4.x; As[q*4+1][m] = a4.y; As[q*4+2][m] = a4.z; As[q*4+3][m] = a4.w;
        }
        {
            #pragma unroll
            for (int i = 0; i < 2; i++){
                int idx = tid*2 + i;
                int r = idx >> 5, c4 = idx & 31;
                int col = n0 + c4*4;
                float4 bv = make_float4(0.f,0.f,0.f,0.f);
                if (col < Nn) bv = *(const float4*)(B + (size_t)(kt+r)*Nn + col);
                *(float4*)(&Bs[r][c4*4]) = bv;
            }
        }
        __syncthreads();
        #pragma unroll
        for (int k = 0; k < KC; k++){
            float4 b4 = *(const float4*)(&Bs[k][tn*4]);
            v2f b01 = (v2f){b4.x, b4.y};
            v2f b23 = (v2f){b4.z, b4.w};
            float4 a0 = *(const float4*)(&As[k][tm*8]);
            float4 a1 = *(const float4*)(&As[k][tm*8+4]);
            float av[8] = {a0.x,a0.y,a0.z,a0.w,a1.x,a1.y,a1.z,a1.w};
            #pragma unroll
            for (int i = 0; i < 8; i++){
                v2f ai = (v2f){av[i], av[i]};
                acc[i][0] = __builtin_elementwise_fma(ai, b01, acc[i][0]);
                acc[i][1] = __builtin_elementwise_fma(ai, b23, acc[i][1]);
            }
        }
        __syncthreads();
    }
    int col = n0 + tn*4;
    if (col < Nn){
        float4 bb = *(const float4*)(bias + col);
        #pragma unroll
        for (int i = 0; i < 8; i++){
            int row = m0 + tm*8 + i;
            float4 o = make_float4(acc[i][0].x+bb.x, acc[i][0].y+bb.y, acc[i][1].x+bb.z, acc[i][1].y+bb.w);
            *(float4*)(C + (size_t)row*Nn + col) = o;
        }
    }
}

// ---------------- job sort: order (row,dir) jobs by descending length (LPT) ----------------
__global__ __launch_bounds__(512) void k_sortjobs(const int* __restrict__ lengths,
        int* __restrict__ jobs, int* __restrict__ counter){
    __shared__ int keys[512];
    __shared__ int vals[512];
    int tid = threadIdx.x;
    keys[tid] = -lengths[tid >> 1];     // ascending sort of -len == descending len
    vals[tid] = tid;
    __syncthreads();
    for (int k = 2; k <= 512; k <<= 1){
        for (int jj = k >> 1; jj > 0; jj >>= 1){
            int ixj = tid ^ jj;
            if (ixj > tid){
                bool up = ((tid & k) == 0);
                int k0 = keys[tid], k1 = keys[ixj];
                if ((k0 > k1) == up){
                    keys[tid] = k1; keys[ixj] = k0;
                    int v0 = vals[tid]; vals[tid] = vals[ixj]; vals[ixj] = v0;
                }
            }
            __syncthreads();
        }
    }
    jobs[tid] = vals[tid];
    if (tid == 0) *counter = 0;
}

// ---------------- LSTM recurrence: one block per job = (batch row, direction) ----------------
// __launch_bounds__(512, 1): VGPR cap 512. Measured occupancy was ~1 block/CU even
// at (512,2), but the allocator capped VGPRs at 100 and spilled the Whh row
// (needs 128 f32/thread). With min-1-wave/EU the row stays fully in registers.
__global__ __launch_bounds__(512, 1) void k_lstm(const float* __restrict__ xg_f, const float* __restrict__ xg_b,
        const float* __restrict__ Whh_f, const float* __restrict__ Whh_b,
        const int* __restrict__ lengths, const int* __restrict__ jobs, int* __restrict__ counter,
        float* __restrict__ lstm_out, int T){
    __shared__ int job_s;
    int j = threadIdx.x;
    if (j == 0) job_s = atomicAdd(counter, 1);
    __syncthreads();
    int job = jobs[job_s];
    int b = job >> 1, dir = job & 1;
    const float* xg  = dir ? xg_b  : xg_f;
    const float* Whh = dir ? Whh_b : Whh_f;
    int len = lengths[b];
    __shared__ __align__(16) float h[128];
    __shared__ float g[512];
    v2f w[64];                                   // full Whh row: 128 VGPRs
    const v2f* wrow = (const v2f*)(Whh + j*128);
    #pragma unroll
    for (int k = 0; k < 64; k++) w[k] = wrow[k];
    if (j < 128) h[j] = 0.f;
    float c = 0.f;
    const float* xgb = xg + (size_t)b*T*512 + j;
    float* lob = lstm_out + (size_t)b*T*256 + dir*128 + j;
    int t0 = dir ? (len-1) : 0;
    float xg_next = xgb[(size_t)t0*512];
    __syncthreads();
    for (int s = 0; s < len; s++){
        int t = dir ? (len-1-s) : s;
        float xgv = xg_next;
        if (s+1 < len){
            int tn = dir ? (len-2-s) : (s+1);
            xg_next = xgb[(size_t)tn*512];      // prefetch next step's gate input
        }
        const float4* h4 = (const float4*)h;
        v2f p0 = (v2f){0.f,0.f}, p1 = (v2f){0.f,0.f}, p2 = (v2f){0.f,0.f}, p3 = (v2f){0.f,0.f};
        #pragma unroll
        for (int k = 0; k < 32; k += 2){
            float4 ha = h4[k+0];
            float4 hb = h4[k+1];
            p0 = __builtin_elementwise_fma(w[2*k+0], (v2f){ha.x,ha.y}, p0);
            p1 = __builtin_elementwise_fma(w[2*k+1], (v2f){ha.z,ha.w}, p1);
            p2 = __builtin_elementwise_fma(w[2*k+2], (v2f){hb.x,hb.y}, p2);
            p3 = __builtin_elementwise_fma(w[2*k+3], (v2f){hb.z,hb.w}, p3);
        }
        g[j] = xgv + (((p0.x+p0.y)+(p1.x+p1.y)) + ((p2.x+p2.y)+(p3.x+p3.y)));
        __syncthreads();
        if (j < 128){
            float gi = g[j], gf = g[128+j], gg = g[256+j], go = g[384+j];
            float cn = sigmf(gf)*c + sigmf(gi)*tanh_f(gg);
            float hn = sigmf(go)*tanh_f(cn);
            c = cn;
            h[j] = hn;
            lob[(size_t)t*256] = hn;
        }
        __syncthreads();
    }
}

// ---------------- attention + context ----------------
__global__ __launch_bounds__(256) void k_attn(const float* __restrict__ lstm_out,
        const float* __restrict__ attn_W, const int* __restrict__ lengths,
        float* __restrict__ context, int T){
    int b = blockIdx.x;
    int tid = threadIdx.x;
    int len = lengths[b];
    __shared__ float sc[TSEQ_MAX];
    __shared__ float red[8];
    int lane = tid & 63, wv = tid >> 6;
    float a0 = attn_W[lane], a1 = attn_W[64+lane], a2 = attn_W[128+lane], a3 = attn_W[192+lane];
    for (int t = wv; t < len; t += 4){
        const float* r = lstm_out + ((size_t)b*T + t)*256;
        float p = r[lane]*a0 + r[64+lane]*a1 + r[128+lane]*a2 + r[192+lane]*a3;
        #pragma unroll
        for (int o = 32; o > 0; o >>= 1) p += __shfl_down(p, o);
        if (lane == 0) sc[t] = p;
    }
    __syncthreads();
    float v = (tid < len) ? sc[tid] : -INFINITY;
    float m = v;
    #pragma unroll
    for (int o = 32; o > 0; o >>= 1) m = fmaxf(m, __shfl_down(m, o));
    if (lane == 0) red[wv] = m;
    __syncthreads();
    float M4 = fmaxf(fmaxf(red[0],red[1]), fmaxf(red[2],red[3]));
    float e = (tid < len) ? __expf(v - M4) : 0.f;
    float ss = e;
    #pragma unroll
    for (int o = 32; o > 0; o >>= 1) ss += __shfl_down(ss, o);
    if (lane == 0) red[4+wv] = ss;
    __syncthreads();
    float S = red[4]+red[5]+red[6]+red[7];
    sc[tid] = e / S;
    __syncthreads();
    float acc = 0.f;
    for (int t = 0; t < len; t++) acc += sc[t] * lstm_out[((size_t)b*T + t)*256 + tid];
    context[b*256 + tid] = acc;
}

extern "C" void kernel_launch(void* const* d_in, const int* in_sizes, int n_in,
                              void* d_out, int out_size, void* d_ws, size_t ws_size,
                              hipStream_t stream) {
    const float* x_coords  = (const float*)d_in[0];
    const float* temporal  = (const float*)d_in[1];
    const int*   edge_idx  = (const int*)  d_in[2];
    const float* edge_w    = (const float*)d_in[3];
    const int*   seq       = (const int*)  d_in[4];
    const float* durations = (const float*)d_in[5];
    const int*   lengths   = (const int*)  d_in[6];
    const float* node_emb  = (const float*)d_in[7];
    const float* gcn1_W    = (const float*)d_in[8];
    const float* gcn1_b    = (const float*)d_in[9];
    const float* gcn2_W    = (const float*)d_in[10];
    const float* gcn2_b    = (const float*)d_in[11];
    const float* dur_W1    = (const float*)d_in[12];
    const float* dur_b1    = (const float*)d_in[13];
    const float* dur_W2    = (const float*)d_in[14];
    const float* dur_b2    = (const float*)d_in[15];
    const float* Wih_f     = (const float*)d_in[16];
    const float* Whh_f     = (const float*)d_in[17];
    const float* b_f       = (const float*)d_in[18];
    const float* Wih_b     = (const float*)d_in[19];
    const float* Whh_b     = (const float*)d_in[20];
    const float* b_b       = (const float*)d_in[21];
    const float* attn_W    = (const float*)d_in[22];
    const float* fc_W      = (const float*)d_in[24];
    const float* fc_b      = (const float*)d_in[25];
    float* out = (float*)d_out;
    float* ws  = (float*)d_ws;

    const int N  = in_sizes[0] / 2;      // 100000
    const int E  = in_sizes[2] / 2;      // 1600000
    const int B  = in_sizes[6];          // 256
    const int T  = in_sizes[4] / B;      // 200
    const int BT = B * T;                // 51200

    // persistent region (floats)
    float* xg_f     = ws + 0;                       // 26,214,400
    float* xg_b     = ws + 26214400;                // 26,214,400
    float* xbuf     = ws + 52428800;                //  8,192,000
    float* lstm_out = ws + 60620800;                // 13,107,200
    float* context  = ws + 73728000;                //     65,536
    float* WihT_f   = ws + 73793536;                //     81,920
    float* WihT_b   = ws + 73875456;                //     81,920  (total ~296 MB)

    // jobs/counter live in the context region: written by k_sortjobs early,
    // consumed by k_lstm, dead before k_attn writes context.
    int* jobs    = (int*)context;          // 512 ints
    int* counter = (int*)context + 512;    // 1 int

    // GCN temporaries overlaid under xg region (all dead before GEMMs write xg)
    float* dis  = ws + 0;            // N
    float* xw1  = ws + 100352;       // N*64
    float* out1 = ws + 6500352;      // N*64
    float* xw2  = ws + 12900352;     // N*128
    float* zbuf = ws + 25700352;     // N*128  (ends 38,500,352)
    int2*  sorted   = (int2*)(ws + 38500352);   // E * 8B
    int*   cnt      = (int*) (ws + 41700352);   // N
    int*   base     = (int*) (ws + 41800352);   // N+1
    int*   cursor   = (int*) (ws + 41900356);   // N
    int*   partials = (int*) (ws + 42000356);   // 128

    const int SCAN_BLOCKS = (N + 1023) / 1024;  // 98

    // ---- job ordering for LSTM load balance ----
    k_sortjobs<<<dim3(1), dim3(512), 0, stream>>>(lengths, jobs, counter);

    // ---- GCN normalization ----
    k_deg_init<<<dim3((N+255)/256), dim3(256), 0, stream>>>(dis, N);
    k_deg_acc <<<dim3((E+255)/256), dim3(256), 0, stream>>>(edge_idx, edge_w, dis, E);
    k_dis     <<<dim3((N+255)/256), dim3(256), 0, stream>>>(dis, N);

    // ---- CSR build (sort edges by destination) ----
    hipMemsetAsync(cnt, 0, (size_t)N*sizeof(int), stream);
    k_count  <<<dim3((E+255)/256), dim3(256), 0, stream>>>(edge_idx, cnt, E);
    k_scan1  <<<dim3(SCAN_BLOCKS), dim3(256), 0, stream>>>(cnt, base, partials, N);
    k_scan2  <<<dim3(1), dim3(128), 0, stream>>>(partials, SCAN_BLOCKS);
    k_scan3  <<<dim3((N+256)/256), dim3(256), 0, stream>>>(base, cursor, partials, N, E);
    k_scatter<<<dim3((E+255)/256), dim3(256), 0, stream>>>(edge_idx, edge_w, dis, cursor, sorted, E);

    // ---- GCN layer 1 ----
    k_xw1    <<<dim3((N+3)/4), dim3(256), 0, stream>>>(x_coords, temporal, node_emb, gcn1_W, xw1, N);
    k_gather1<<<dim3((N+3)/4), dim3(256), 0, stream>>>(sorted, base, dis, xw1, gcn1_b, out1, N);

    // ---- GCN layer 2 ----
    k_xw2    <<<dim3((N+1)/2), dim3(256), 0, stream>>>(out1, gcn2_W, xw2, N);
    k_gather2<<<dim3((N+1)/2), dim3(256), 0, stream>>>(sorted, base, dis, xw2, gcn2_b, zbuf, N);

    // ---- sequence features ----
    k_build_x<<<dim3(BT), dim3(192), 0, stream>>>(zbuf, seq, durations, dur_W1, dur_b1, dur_W2, dur_b2, xbuf);

    // ---- input-gate GEMMs ----
    k_transpose_wih<<<dim3(320), dim3(256), 0, stream>>>(Wih_f, Wih_b, WihT_f, WihT_b);
    k_gemm<<<dim3(512/NT, BT/MT), dim3(256), 0, stream>>>(xbuf, WihT_f, b_f, xg_f, BT, 512, 160);
    k_gemm<<<dim3(512/NT, BT/MT), dim3(256), 0, stream>>>(xbuf, WihT_b, b_b, xg_b, BT, 512, 160);

    // ---- BiLSTM recurrence (LPT job order) ----
    k_lstm<<<dim3(2*B), dim3(512), 0, stream>>>(xg_f, xg_b, Whh_f, Whh_b, lengths, jobs, counter, lstm_out, T);

    // ---- attention ----
    k_attn<<<dim3(B), dim3(256), 0, stream>>>(lstm_out, attn_W, lengths, context, T);

    // ---- final FC: (256 x 256) @ (256 x 100000) + fc_b ----
    k_gemm<<<dim3((N + NT - 1)/NT, B/MT), dim3(256), 0, stream>>>(context, fc_W, fc_b, out, B, N, 256);
}